// Round 17
// baseline (225.531 us; speedup 1.0000x reference)
//
#include <hip/hip_runtime.h>
#include <hip/hip_bf16.h>
#include <math.h>

#define NPTS 2048
#define BN   16384
#define KNN_K 32
typedef unsigned long long u64;
typedef float f32x4 __attribute__((ext_vector_type(4)));
#define INF64 0xFFFFFFFFFFFFFFFFull

__device__ __forceinline__ u64 umin64(u64 a, u64 b) { return a < b ? a : b; }

// ---------------- Kernel A: exact kNN, TWO queries per wave ----------------
// r14-16 lessons: kernel is stall-bound on serial cross-lane chains (~60
// dependent shfl/swizzle ops); occupancy and DS-vs-VMEM moves were null.
// Fix: 2 queries/wave -> every serial chain becomes 2 independent chains
// interleaved (ILP hides latency), and candidate loads are shared.
// VGPR ~90-110: cap (256,4)=128 (r14: caps <~48 spill d[] to scratch).
__global__ __launch_bounds__(256, 4) void knn_kernel(const float* __restrict__ pts,
                                                     int* __restrict__ knn) {
    __shared__ u64 surv[8][64];                      // 4 KB; wave w -> rows 2w,2w+1
    const int b = blockIdx.x >> 8;                   // 256 blocks per batch
    const int qbase = (blockIdx.x & 255) << 3;       // 8 queries per block
    const float* pb = pts + (size_t)b * NPTS * 3;
    const int wave = threadIdx.x >> 6, lane = threadIdx.x & 63;
    const int q0 = qbase + wave * 2, q1 = q0 + 1;
    const float qx0 = pb[q0 * 3 + 0], qy0 = pb[q0 * 3 + 1], qz0 = pb[q0 * 3 + 2];
    const float qx1 = pb[q1 * 3 + 0], qy1 = pb[q1 * 3 + 1], qz1 = pb[q1 * 3 + 2];

    // distances for both queries; candidate loads shared (L1/L2-resident slab)
    float d0[32], d1[32];
#pragma unroll
    for (int t = 0; t < 32; ++t) {
        int j = t * 64 + lane;
        float x = pb[j * 3 + 0], y = pb[j * 3 + 1], z = pb[j * 3 + 2];
        float dx0 = __fsub_rn(qx0, x), dy0 = __fsub_rn(qy0, y), dz0 = __fsub_rn(qz0, z);
        float dx1 = __fsub_rn(qx1, x), dy1 = __fsub_rn(qy1, y), dz1 = __fsub_rn(qz1, z);
        d0[t] = __fsqrt_rn(__fadd_rn(__fadd_rn(__fmul_rn(dx0, dx0), __fmul_rn(dy0, dy0)),
                                     __fmul_rn(dz0, dz0)));
        d1[t] = __fsqrt_rn(__fadd_rn(__fadd_rn(__fmul_rn(dx1, dx1), __fmul_rn(dy1, dy1)),
                                     __fmul_rn(dz1, dz1)));
    }

    float v0 = d0[0], v1 = d1[0];
#pragma unroll
    for (int t = 1; t < 32; ++t) { v0 = fminf(v0, d0[t]); v1 = fminf(v1, d1[t]); }

    // two interleaved bitonic sorts of the 64 lane-minima
#pragma unroll
    for (int k = 2; k <= 64; k <<= 1) {
#pragma unroll
        for (int j = k >> 1; j > 0; j >>= 1) {
            float o0 = __shfl_xor(v0, j, 64);
            float o1 = __shfl_xor(v1, j, 64);
            bool keepmin = (((lane & j) == 0) == ((lane & k) == 0));
            float mn0 = fminf(v0, o0), mx0 = fmaxf(v0, o0);
            float mn1 = fminf(v1, o1), mx1 = fmaxf(v1, o1);
            v0 = keepmin ? mn0 : mx0;
            v1 = keepmin ? mn1 : mx1;
        }
    }
    float Tpre0 = __shfl(v0, 31, 64);   // >= 32nd-smallest distance, q0
    float Tpre1 = __shfl(v1, 31, 64);   // >= 32nd-smallest distance, q1

    // interleaved ballot-compact of both survivor sets
    u64* sw0 = surv[wave * 2 + 0];
    u64* sw1 = surv[wave * 2 + 1];
    unsigned cnt0 = 0, cnt1 = 0;
#pragma unroll
    for (int t = 0; t < 32; ++t) {
        bool s0 = (d0[t] <= Tpre0);
        bool s1 = (d1[t] <= Tpre1);
        u64 m0 = __ballot(s0);
        u64 m1 = __ballot(s1);
        unsigned idx = (unsigned)(t * 64 + lane);
        if (s0) {
            unsigned pos = cnt0 + (unsigned)__popcll(m0 & ((1ull << lane) - 1ull));
            if (pos < 64) sw0[pos] = ((u64)__float_as_uint(d0[t]) << 32) | idx;
        }
        if (s1) {
            unsigned pos = cnt1 + (unsigned)__popcll(m1 & ((1ull << lane) - 1ull));
            if (pos < 64) sw1[pos] = ((u64)__float_as_uint(d1[t]) << 32) | idx;
        }
        cnt0 += (unsigned)__popcll(m0);
        cnt1 += (unsigned)__popcll(m1);
    }

    int* kout0 = knn + ((size_t)b * NPTS + q0) * KNN_K;
    int* kout1 = knn + ((size_t)b * NPTS + q1) * KNN_K;
    __asm__ volatile("s_waitcnt lgkmcnt(0)" ::: "memory");  // own-wave LDS W->R fence

    if (cnt0 <= 64 && cnt1 <= 64) {
        u64 k0 = (lane < (int)cnt0) ? sw0[lane] : INF64;
        u64 k1 = (lane < (int)cnt1) ? sw1[lane] : INF64;
#pragma unroll
        for (int k = 2; k <= 64; k <<= 1) {
#pragma unroll
            for (int j = k >> 1; j > 0; j >>= 1) {
                u64 o0 = __shfl_xor(k0, j, 64);
                u64 o1 = __shfl_xor(k1, j, 64);
                bool keepmin = (((lane & j) == 0) == ((lane & k) == 0));
                bool lt0 = k0 < o0, lt1 = k1 < o1;
                u64 mn0 = lt0 ? k0 : o0, mx0 = lt0 ? o0 : k0;
                u64 mn1 = lt1 ? k1 : o1, mx1 = lt1 ? o1 : k1;
                k0 = keepmin ? mn0 : mx0;
                k1 = keepmin ? mn1 : mx1;
            }
        }
        if (lane < KNN_K) {
            kout0[lane] = (int)(unsigned)(k0 & 0xFFFFFFFFull);
            kout1[lane] = (int)(unsigned)(k1 & 0xFFFFFFFFull);
        }
    } else {
        // rare exact fallback (either survivor set > 64): full extraction, per query
        unsigned fmask = 0xFFFFFFFFu;
        for (int r = 0; r < KNN_K; ++r) {
            u64 mm = INF64;
#pragma unroll
            for (int t = 0; t < 32; ++t) {
                u64 kk = ((u64)__float_as_uint(d0[t]) << 32) | (unsigned)(t * 64 + lane);
                mm = umin64(mm, ((fmask >> t) & 1u) ? kk : INF64);
            }
#pragma unroll
            for (int s = 1; s < 64; s <<= 1) mm = umin64(mm, __shfl_xor(mm, s, 64));
            unsigned j = (unsigned)(mm & 0xFFFFFFFFull);
            if (lane == (int)(j & 63)) fmask &= ~(1u << (j >> 6));
            if (lane == 0) kout0[r] = (int)j;
        }
        fmask = 0xFFFFFFFFu;
        for (int r = 0; r < KNN_K; ++r) {
            u64 mm = INF64;
#pragma unroll
            for (int t = 0; t < 32; ++t) {
                u64 kk = ((u64)__float_as_uint(d1[t]) << 32) | (unsigned)(t * 64 + lane);
                mm = umin64(mm, ((fmask >> t) & 1u) ? kk : INF64);
            }
#pragma unroll
            for (int s = 1; s < 64; s <<= 1) mm = umin64(mm, __shfl_xor(mm, s, 64));
            unsigned j = (unsigned)(mm & 0xFFFFFFFFull);
            if (lane == (int)(j & 63)) fmask &= ~(1u << (j >> 6));
            if (lane == 0) kout1[r] = (int)j;
        }
    }
}

// ---------------- Kernel B: fused MLP (layers 1..3) -> f3 [BN][256] ----------------
// (r13/r15 measured-best config: Pp=4, 1024 blocks, own-wave lgkmcnt fence.
//  r16's Pp=8 was neutral-to-worse -> reverted.)
__global__ __launch_bounds__(256, 8) void mlp123_kernel(const float* __restrict__ pts,
        const float* __restrict__ W1, const float* __restrict__ b1,
        const float* __restrict__ W2, const float* __restrict__ b2,
        const float* __restrict__ W3, const float* __restrict__ b3,
        float* __restrict__ f3) {
    __shared__ float h2s[16][128];   // 8 KB
    const int tid = threadIdx.x;
    const int wv = tid >> 6, lane = tid & 63;
    const int p0 = blockIdx.x << 4;
    const int pbase = wv * 4;        // this wave's local points

    // ---- phase 0: layers 1+2 for this wave's 4 points ----
    {
        const float w1a = W1[lane], w1b = W1[64 + lane], w1c = W1[128 + lane];
        const float b1v = b1[lane];
        float h1v[4];
#pragma unroll
        for (int p = 0; p < 4; ++p) {
            const int pp = __builtin_amdgcn_readfirstlane(p0 + pbase + p);
            const float* ptp = pts + (size_t)pp * 3;
            h1v[p] = fmaxf(fmaf(ptp[0], w1a, fmaf(ptp[1], w1b, fmaf(ptp[2], w1c, b1v))), 0.f);
        }
        float2 b2v = *(const float2*)(b2 + 2 * lane);
        float a0[4], a1[4];
#pragma unroll
        for (int p = 0; p < 4; ++p) { a0[p] = b2v.x; a1[p] = b2v.y; }
#pragma unroll
        for (int i = 0; i < 64; ++i) {
            float2 w = *(const float2*)(W2 + i * 128 + 2 * lane);
#pragma unroll
            for (int p = 0; p < 4; ++p) {
                float h = __shfl(h1v[p], i, 64);
                a0[p] = fmaf(h, w.x, a0[p]);
                a1[p] = fmaf(h, w.y, a1[p]);
            }
        }
#pragma unroll
        for (int p = 0; p < 4; ++p)
            *(float2*)&h2s[pbase + p][2 * lane] =
                make_float2(fmaxf(a0[p], 0.f), fmaxf(a1[p], 0.f));
    }
    // own-wave LDS write->read fence (phase 1 reads only this wave's rows)
    __asm__ volatile("s_waitcnt lgkmcnt(0)" ::: "memory");

    // ---- phase 1: layer 3; lane -> channels c0..c0+3, points pbase..pbase+3 ----
    const int c0 = lane * 4;
    float4 acc0 = make_float4(0.f, 0.f, 0.f, 0.f);
    float4 acc1 = make_float4(0.f, 0.f, 0.f, 0.f);
    float4 acc2 = make_float4(0.f, 0.f, 0.f, 0.f);
    float4 acc3 = make_float4(0.f, 0.f, 0.f, 0.f);
    for (int k4 = 0; k4 < 32; ++k4) {
        float4 h0 = *(const float4*)&h2s[pbase + 0][k4 * 4];
        float4 h1 = *(const float4*)&h2s[pbase + 1][k4 * 4];
        float4 h2 = *(const float4*)&h2s[pbase + 2][k4 * 4];
        float4 h3 = *(const float4*)&h2s[pbase + 3][k4 * 4];
#pragma unroll
        for (int u = 0; u < 4; ++u) {
            float4 w = *(const float4*)(W3 + (size_t)(k4 * 4 + u) * 256 + c0);
            float e0 = (u == 0) ? h0.x : (u == 1) ? h0.y : (u == 2) ? h0.z : h0.w;
            float e1 = (u == 0) ? h1.x : (u == 1) ? h1.y : (u == 2) ? h1.z : h1.w;
            float e2 = (u == 0) ? h2.x : (u == 1) ? h2.y : (u == 2) ? h2.z : h2.w;
            float e3 = (u == 0) ? h3.x : (u == 1) ? h3.y : (u == 2) ? h3.z : h3.w;
            acc0.x = fmaf(e0, w.x, acc0.x); acc0.y = fmaf(e0, w.y, acc0.y);
            acc0.z = fmaf(e0, w.z, acc0.z); acc0.w = fmaf(e0, w.w, acc0.w);
            acc1.x = fmaf(e1, w.x, acc1.x); acc1.y = fmaf(e1, w.y, acc1.y);
            acc1.z = fmaf(e1, w.z, acc1.z); acc1.w = fmaf(e1, w.w, acc1.w);
            acc2.x = fmaf(e2, w.x, acc2.x); acc2.y = fmaf(e2, w.y, acc2.y);
            acc2.z = fmaf(e2, w.z, acc2.z); acc2.w = fmaf(e2, w.w, acc2.w);
            acc3.x = fmaf(e3, w.x, acc3.x); acc3.y = fmaf(e3, w.y, acc3.y);
            acc3.z = fmaf(e3, w.z, acc3.z); acc3.w = fmaf(e3, w.w, acc3.w);
        }
    }
    float4 bb = *(const float4*)(b3 + c0);
    float4 r0 = make_float4(fmaxf(acc0.x + bb.x, 0.f), fmaxf(acc0.y + bb.y, 0.f),
                            fmaxf(acc0.z + bb.z, 0.f), fmaxf(acc0.w + bb.w, 0.f));
    float4 r1 = make_float4(fmaxf(acc1.x + bb.x, 0.f), fmaxf(acc1.y + bb.y, 0.f),
                            fmaxf(acc1.z + bb.z, 0.f), fmaxf(acc1.w + bb.w, 0.f));
    float4 r2 = make_float4(fmaxf(acc2.x + bb.x, 0.f), fmaxf(acc2.y + bb.y, 0.f),
                            fmaxf(acc2.z + bb.z, 0.f), fmaxf(acc2.w + bb.w, 0.f));
    float4 r3 = make_float4(fmaxf(acc3.x + bb.x, 0.f), fmaxf(acc3.y + bb.y, 0.f),
                            fmaxf(acc3.z + bb.z, 0.f), fmaxf(acc3.w + bb.w, 0.f));
    float* ob = f3 + ((size_t)(p0 + pbase)) * 256 + c0;
    *(float4*)(ob)           = r0;
    *(float4*)(ob + 256)     = r1;
    *(float4*)(ob + 512)     = r2;
    *(float4*)(ob + 768)     = r3;
}

// ---------------- Kernel C: gather + mean; batch pinned to XCD via blockIdx&7 ----------------
// (r15 measured-best config; r16's idx-prefetch was neutral -> reverted)
__global__ __launch_bounds__(256) void gather_mean_kernel(const float* __restrict__ f3,
        const int* __restrict__ knn, float* __restrict__ out) {
    int wave = threadIdx.x >> 6, lane = threadIdx.x & 63;
    int b  = blockIdx.x & 7;
    int qg = blockIdx.x >> 3;          // 0..511
    int q  = b * NPTS + qg * 4 + wave;
    const int* kq = knn + (size_t)q * KNN_K;
    const float4* fb = (const float4*)(f3 + (size_t)b * NPTS * 256);
    float4 acc = make_float4(0.f, 0.f, 0.f, 0.f);
#pragma unroll
    for (int k = 0; k < KNN_K; ++k) {
        int j = kq[k];
        float4 v2 = fb[(size_t)j * 64 + lane];
        acc.x += v2.x; acc.y += v2.y; acc.z += v2.z; acc.w += v2.w;
    }
    f32x4 r;
    r.x = acc.x * 0.03125f; r.y = acc.y * 0.03125f;
    r.z = acc.z * 0.03125f; r.w = acc.w * 0.03125f;
    __builtin_nontemporal_store(r, (f32x4*)(out + (size_t)q * 256 + lane * 4));
}

extern "C" void kernel_launch(void* const* d_in, const int* in_sizes, int n_in,
                              void* d_out, int out_size, void* d_ws, size_t ws_size,
                              hipStream_t stream) {
    const float* pts = (const float*)d_in[0];
    const float* W1  = (const float*)d_in[1];
    const float* b1  = (const float*)d_in[2];
    const float* W2  = (const float*)d_in[3];
    const float* b2  = (const float*)d_in[4];
    const float* W3  = (const float*)d_in[5];
    const float* b3  = (const float*)d_in[6];
    float* out = (float*)d_out;
    char* ws = (char*)d_ws;
    int*   knn = (int*)ws;                               // 2 MB
    float* f3  = (float*)(ws + ((size_t)2 << 20));       // 16.8 MB

    hipLaunchKernelGGL(knn_kernel,         dim3(2048), dim3(256), 0, stream, pts, knn);
    hipLaunchKernelGGL(mlp123_kernel,      dim3(1024), dim3(256), 0, stream,
                       pts, W1, b1, W2, b2, W3, b3, f3);
    hipLaunchKernelGGL(gather_mean_kernel, dim3(4096), dim3(256), 0, stream, f3, knn, out);
}

// Round 18
// 214.277 us; speedup vs baseline: 1.0525x; 1.0525x over previous
//
#include <hip/hip_runtime.h>
#include <hip/hip_bf16.h>
#include <math.h>

#define NPTS 2048
#define BN   16384
#define KNN_K 32
typedef unsigned long long u64;
typedef float f32x4 __attribute__((ext_vector_type(4)));
#define INF64 0xFFFFFFFFFFFFFFFFull

__device__ __forceinline__ u64 umin64(u64 a, u64 b) { return a < b ? a : b; }

// ---------------- Kernel A: exact kNN, TWO queries per wave ----------------
// r17 lesson: __launch_bounds__(256,4) made the allocator SQUEEZE to 64 VGPR
// (its 8-waves/EU heuristic) and spill d0[]+d1[] (9.4MB FETCH, 2x slower).
// Bare __launch_bounds__(256) (r16: compiler chose 68 for 1q version) lets it
// take the ~110-130 this kernel needs. NO min-waves hint on this kernel, ever.
__global__ __launch_bounds__(256) void knn_kernel(const float* __restrict__ pts,
                                                  int* __restrict__ knn) {
    __shared__ u64 surv[8][64];                      // 4 KB; wave w -> rows 2w,2w+1
    const int b = blockIdx.x >> 8;                   // 256 blocks per batch
    const int qbase = (blockIdx.x & 255) << 3;       // 8 queries per block
    const float* pb = pts + (size_t)b * NPTS * 3;
    const int wave = threadIdx.x >> 6, lane = threadIdx.x & 63;
    const int q0 = qbase + wave * 2, q1 = q0 + 1;
    const float qx0 = pb[q0 * 3 + 0], qy0 = pb[q0 * 3 + 1], qz0 = pb[q0 * 3 + 2];
    const float qx1 = pb[q1 * 3 + 0], qy1 = pb[q1 * 3 + 1], qz1 = pb[q1 * 3 + 2];

    // distances for both queries; candidate loads shared (L1/L2-resident slab)
    float d0[32], d1[32];
#pragma unroll
    for (int t = 0; t < 32; ++t) {
        int j = t * 64 + lane;
        float x = pb[j * 3 + 0], y = pb[j * 3 + 1], z = pb[j * 3 + 2];
        float dx0 = __fsub_rn(qx0, x), dy0 = __fsub_rn(qy0, y), dz0 = __fsub_rn(qz0, z);
        float dx1 = __fsub_rn(qx1, x), dy1 = __fsub_rn(qy1, y), dz1 = __fsub_rn(qz1, z);
        d0[t] = __fsqrt_rn(__fadd_rn(__fadd_rn(__fmul_rn(dx0, dx0), __fmul_rn(dy0, dy0)),
                                     __fmul_rn(dz0, dz0)));
        d1[t] = __fsqrt_rn(__fadd_rn(__fadd_rn(__fmul_rn(dx1, dx1), __fmul_rn(dy1, dy1)),
                                     __fmul_rn(dz1, dz1)));
    }

    float v0 = d0[0], v1 = d1[0];
#pragma unroll
    for (int t = 1; t < 32; ++t) { v0 = fminf(v0, d0[t]); v1 = fminf(v1, d1[t]); }

    // two interleaved bitonic sorts of the 64 lane-minima
#pragma unroll
    for (int k = 2; k <= 64; k <<= 1) {
#pragma unroll
        for (int j = k >> 1; j > 0; j >>= 1) {
            float o0 = __shfl_xor(v0, j, 64);
            float o1 = __shfl_xor(v1, j, 64);
            bool keepmin = (((lane & j) == 0) == ((lane & k) == 0));
            float mn0 = fminf(v0, o0), mx0 = fmaxf(v0, o0);
            float mn1 = fminf(v1, o1), mx1 = fmaxf(v1, o1);
            v0 = keepmin ? mn0 : mx0;
            v1 = keepmin ? mn1 : mx1;
        }
    }
    float Tpre0 = __shfl(v0, 31, 64);   // >= 32nd-smallest distance, q0
    float Tpre1 = __shfl(v1, 31, 64);   // >= 32nd-smallest distance, q1

    // interleaved ballot-compact of both survivor sets
    u64* sw0 = surv[wave * 2 + 0];
    u64* sw1 = surv[wave * 2 + 1];
    unsigned cnt0 = 0, cnt1 = 0;
#pragma unroll
    for (int t = 0; t < 32; ++t) {
        bool s0 = (d0[t] <= Tpre0);
        bool s1 = (d1[t] <= Tpre1);
        u64 m0 = __ballot(s0);
        u64 m1 = __ballot(s1);
        unsigned idx = (unsigned)(t * 64 + lane);
        if (s0) {
            unsigned pos = cnt0 + (unsigned)__popcll(m0 & ((1ull << lane) - 1ull));
            if (pos < 64) sw0[pos] = ((u64)__float_as_uint(d0[t]) << 32) | idx;
        }
        if (s1) {
            unsigned pos = cnt1 + (unsigned)__popcll(m1 & ((1ull << lane) - 1ull));
            if (pos < 64) sw1[pos] = ((u64)__float_as_uint(d1[t]) << 32) | idx;
        }
        cnt0 += (unsigned)__popcll(m0);
        cnt1 += (unsigned)__popcll(m1);
    }

    int* kout0 = knn + ((size_t)b * NPTS + q0) * KNN_K;
    int* kout1 = knn + ((size_t)b * NPTS + q1) * KNN_K;
    __asm__ volatile("s_waitcnt lgkmcnt(0)" ::: "memory");  // own-wave LDS W->R fence

    if (cnt0 <= 64 && cnt1 <= 64) {
        u64 k0 = (lane < (int)cnt0) ? sw0[lane] : INF64;
        u64 k1 = (lane < (int)cnt1) ? sw1[lane] : INF64;
#pragma unroll
        for (int k = 2; k <= 64; k <<= 1) {
#pragma unroll
            for (int j = k >> 1; j > 0; j >>= 1) {
                u64 o0 = __shfl_xor(k0, j, 64);
                u64 o1 = __shfl_xor(k1, j, 64);
                bool keepmin = (((lane & j) == 0) == ((lane & k) == 0));
                bool lt0 = k0 < o0, lt1 = k1 < o1;
                u64 mn0 = lt0 ? k0 : o0, mx0 = lt0 ? o0 : k0;
                u64 mn1 = lt1 ? k1 : o1, mx1 = lt1 ? o1 : k1;
                k0 = keepmin ? mn0 : mx0;
                k1 = keepmin ? mn1 : mx1;
            }
        }
        if (lane < KNN_K) {
            kout0[lane] = (int)(unsigned)(k0 & 0xFFFFFFFFull);
            kout1[lane] = (int)(unsigned)(k1 & 0xFFFFFFFFull);
        }
    } else {
        // rare exact fallback (either survivor set > 64): full extraction, per query
        unsigned fmask = 0xFFFFFFFFu;
        for (int r = 0; r < KNN_K; ++r) {
            u64 mm = INF64;
#pragma unroll
            for (int t = 0; t < 32; ++t) {
                u64 kk = ((u64)__float_as_uint(d0[t]) << 32) | (unsigned)(t * 64 + lane);
                mm = umin64(mm, ((fmask >> t) & 1u) ? kk : INF64);
            }
#pragma unroll
            for (int s = 1; s < 64; s <<= 1) mm = umin64(mm, __shfl_xor(mm, s, 64));
            unsigned j = (unsigned)(mm & 0xFFFFFFFFull);
            if (lane == (int)(j & 63)) fmask &= ~(1u << (j >> 6));
            if (lane == 0) kout0[r] = (int)j;
        }
        fmask = 0xFFFFFFFFu;
        for (int r = 0; r < KNN_K; ++r) {
            u64 mm = INF64;
#pragma unroll
            for (int t = 0; t < 32; ++t) {
                u64 kk = ((u64)__float_as_uint(d1[t]) << 32) | (unsigned)(t * 64 + lane);
                mm = umin64(mm, ((fmask >> t) & 1u) ? kk : INF64);
            }
#pragma unroll
            for (int s = 1; s < 64; s <<= 1) mm = umin64(mm, __shfl_xor(mm, s, 64));
            unsigned j = (unsigned)(mm & 0xFFFFFFFFull);
            if (lane == (int)(j & 63)) fmask &= ~(1u << (j >> 6));
            if (lane == 0) kout1[r] = (int)j;
        }
    }
}

// ---------------- Kernel B: fused MLP (layers 1..3) -> f3 [BN][256] ----------------
// (r13/r15 measured-best config: Pp=4, 1024 blocks, own-wave lgkmcnt fence)
__global__ __launch_bounds__(256, 8) void mlp123_kernel(const float* __restrict__ pts,
        const float* __restrict__ W1, const float* __restrict__ b1,
        const float* __restrict__ W2, const float* __restrict__ b2,
        const float* __restrict__ W3, const float* __restrict__ b3,
        float* __restrict__ f3) {
    __shared__ float h2s[16][128];   // 8 KB
    const int tid = threadIdx.x;
    const int wv = tid >> 6, lane = tid & 63;
    const int p0 = blockIdx.x << 4;
    const int pbase = wv * 4;        // this wave's local points

    // ---- phase 0: layers 1+2 for this wave's 4 points ----
    {
        const float w1a = W1[lane], w1b = W1[64 + lane], w1c = W1[128 + lane];
        const float b1v = b1[lane];
        float h1v[4];
#pragma unroll
        for (int p = 0; p < 4; ++p) {
            const int pp = __builtin_amdgcn_readfirstlane(p0 + pbase + p);
            const float* ptp = pts + (size_t)pp * 3;
            h1v[p] = fmaxf(fmaf(ptp[0], w1a, fmaf(ptp[1], w1b, fmaf(ptp[2], w1c, b1v))), 0.f);
        }
        float2 b2v = *(const float2*)(b2 + 2 * lane);
        float a0[4], a1[4];
#pragma unroll
        for (int p = 0; p < 4; ++p) { a0[p] = b2v.x; a1[p] = b2v.y; }
#pragma unroll
        for (int i = 0; i < 64; ++i) {
            float2 w = *(const float2*)(W2 + i * 128 + 2 * lane);
#pragma unroll
            for (int p = 0; p < 4; ++p) {
                float h = __shfl(h1v[p], i, 64);
                a0[p] = fmaf(h, w.x, a0[p]);
                a1[p] = fmaf(h, w.y, a1[p]);
            }
        }
#pragma unroll
        for (int p = 0; p < 4; ++p)
            *(float2*)&h2s[pbase + p][2 * lane] =
                make_float2(fmaxf(a0[p], 0.f), fmaxf(a1[p], 0.f));
    }
    // own-wave LDS write->read fence (phase 1 reads only this wave's rows)
    __asm__ volatile("s_waitcnt lgkmcnt(0)" ::: "memory");

    // ---- phase 1: layer 3; lane -> channels c0..c0+3, points pbase..pbase+3 ----
    const int c0 = lane * 4;
    float4 acc0 = make_float4(0.f, 0.f, 0.f, 0.f);
    float4 acc1 = make_float4(0.f, 0.f, 0.f, 0.f);
    float4 acc2 = make_float4(0.f, 0.f, 0.f, 0.f);
    float4 acc3 = make_float4(0.f, 0.f, 0.f, 0.f);
    for (int k4 = 0; k4 < 32; ++k4) {
        float4 h0 = *(const float4*)&h2s[pbase + 0][k4 * 4];
        float4 h1 = *(const float4*)&h2s[pbase + 1][k4 * 4];
        float4 h2 = *(const float4*)&h2s[pbase + 2][k4 * 4];
        float4 h3 = *(const float4*)&h2s[pbase + 3][k4 * 4];
#pragma unroll
        for (int u = 0; u < 4; ++u) {
            float4 w = *(const float4*)(W3 + (size_t)(k4 * 4 + u) * 256 + c0);
            float e0 = (u == 0) ? h0.x : (u == 1) ? h0.y : (u == 2) ? h0.z : h0.w;
            float e1 = (u == 0) ? h1.x : (u == 1) ? h1.y : (u == 2) ? h1.z : h1.w;
            float e2 = (u == 0) ? h2.x : (u == 1) ? h2.y : (u == 2) ? h2.z : h2.w;
            float e3 = (u == 0) ? h3.x : (u == 1) ? h3.y : (u == 2) ? h3.z : h3.w;
            acc0.x = fmaf(e0, w.x, acc0.x); acc0.y = fmaf(e0, w.y, acc0.y);
            acc0.z = fmaf(e0, w.z, acc0.z); acc0.w = fmaf(e0, w.w, acc0.w);
            acc1.x = fmaf(e1, w.x, acc1.x); acc1.y = fmaf(e1, w.y, acc1.y);
            acc1.z = fmaf(e1, w.z, acc1.z); acc1.w = fmaf(e1, w.w, acc1.w);
            acc2.x = fmaf(e2, w.x, acc2.x); acc2.y = fmaf(e2, w.y, acc2.y);
            acc2.z = fmaf(e2, w.z, acc2.z); acc2.w = fmaf(e2, w.w, acc2.w);
            acc3.x = fmaf(e3, w.x, acc3.x); acc3.y = fmaf(e3, w.y, acc3.y);
            acc3.z = fmaf(e3, w.z, acc3.z); acc3.w = fmaf(e3, w.w, acc3.w);
        }
    }
    float4 bb = *(const float4*)(b3 + c0);
    float4 r0 = make_float4(fmaxf(acc0.x + bb.x, 0.f), fmaxf(acc0.y + bb.y, 0.f),
                            fmaxf(acc0.z + bb.z, 0.f), fmaxf(acc0.w + bb.w, 0.f));
    float4 r1 = make_float4(fmaxf(acc1.x + bb.x, 0.f), fmaxf(acc1.y + bb.y, 0.f),
                            fmaxf(acc1.z + bb.z, 0.f), fmaxf(acc1.w + bb.w, 0.f));
    float4 r2 = make_float4(fmaxf(acc2.x + bb.x, 0.f), fmaxf(acc2.y + bb.y, 0.f),
                            fmaxf(acc2.z + bb.z, 0.f), fmaxf(acc2.w + bb.w, 0.f));
    float4 r3 = make_float4(fmaxf(acc3.x + bb.x, 0.f), fmaxf(acc3.y + bb.y, 0.f),
                            fmaxf(acc3.z + bb.z, 0.f), fmaxf(acc3.w + bb.w, 0.f));
    float* ob = f3 + ((size_t)(p0 + pbase)) * 256 + c0;
    *(float4*)(ob)           = r0;
    *(float4*)(ob + 256)     = r1;
    *(float4*)(ob + 512)     = r2;
    *(float4*)(ob + 768)     = r3;
}

// ---------------- Kernel C: gather + mean; batch pinned to XCD via blockIdx&7 ----------------
__global__ __launch_bounds__(256) void gather_mean_kernel(const float* __restrict__ f3,
        const int* __restrict__ knn, float* __restrict__ out) {
    int wave = threadIdx.x >> 6, lane = threadIdx.x & 63;
    int b  = blockIdx.x & 7;
    int qg = blockIdx.x >> 3;          // 0..511
    int q  = b * NPTS + qg * 4 + wave;
    const int* kq = knn + (size_t)q * KNN_K;
    const float4* fb = (const float4*)(f3 + (size_t)b * NPTS * 256);
    float4 acc = make_float4(0.f, 0.f, 0.f, 0.f);
#pragma unroll
    for (int k = 0; k < KNN_K; ++k) {
        int j = kq[k];
        float4 v2 = fb[(size_t)j * 64 + lane];
        acc.x += v2.x; acc.y += v2.y; acc.z += v2.z; acc.w += v2.w;
    }
    f32x4 r;
    r.x = acc.x * 0.03125f; r.y = acc.y * 0.03125f;
    r.z = acc.z * 0.03125f; r.w = acc.w * 0.03125f;
    __builtin_nontemporal_store(r, (f32x4*)(out + (size_t)q * 256 + lane * 4));
}

extern "C" void kernel_launch(void* const* d_in, const int* in_sizes, int n_in,
                              void* d_out, int out_size, void* d_ws, size_t ws_size,
                              hipStream_t stream) {
    const float* pts = (const float*)d_in[0];
    const float* W1  = (const float*)d_in[1];
    const float* b1  = (const float*)d_in[2];
    const float* W2  = (const float*)d_in[3];
    const float* b2  = (const float*)d_in[4];
    const float* W3  = (const float*)d_in[5];
    const float* b3  = (const float*)d_in[6];
    float* out = (float*)d_out;
    char* ws = (char*)d_ws;
    int*   knn = (int*)ws;                               // 2 MB
    float* f3  = (float*)(ws + ((size_t)2 << 20));       // 16.8 MB

    hipLaunchKernelGGL(knn_kernel,         dim3(2048), dim3(256), 0, stream, pts, knn);
    hipLaunchKernelGGL(mlp123_kernel,      dim3(1024), dim3(256), 0, stream,
                       pts, W1, b1, W2, b2, W3, b3, f3);
    hipLaunchKernelGGL(gather_mean_kernel, dim3(4096), dim3(256), 0, stream, f3, knn, out);
}